// Round 2
// baseline (2046.741 us; speedup 1.0000x reference)
//
#include <hip/hip_runtime.h>
#include <hip/hip_bf16.h>

#define BB 32
#define NN 2048
#define DD 512
#define DGG 1024
#define CC 32          // scan chunks per sequence
#define LLEN 64        // scan chunk length (CC*LLEN == NN)

typedef short bf16x8 __attribute__((ext_vector_type(8)));
typedef float f32x4  __attribute__((ext_vector_type(4)));

__device__ __forceinline__ unsigned short f2bf(float f){
    __hip_bfloat16 h = __float2bfloat16(f);
    return *reinterpret_cast<unsigned short*>(&h);
}
__device__ __forceinline__ float bf2f(unsigned short u){
    unsigned int x = ((unsigned int)u) << 16;
    return __uint_as_float(x);
}
__device__ __forceinline__ float sigm(float x){ return 1.0f/(1.0f + __expf(-x)); }

// ---------------------------------------------------------------------------
// 64x64-tile bf16 MFMA GEMM.  All outputs bf16.
//   MODE 0: out0 = A@B0 + bias0
//   MODE 1: triple i,f,g -> lam, u, g
//   MODE 2: dual GLU -> v = silu(A@B0+b0) * (A@B1+b1)
// ABF16: A operand already bf16 (else fp32, cast during staging).
// ---------------------------------------------------------------------------
template<int MODE, int NB, bool ABF16>
__global__ __launch_bounds__(256)
void gemm_kernel(const void* __restrict__ Ap,
                 const float* __restrict__ Bm0, const float* __restrict__ Bm1,
                 const float* __restrict__ Bm2,
                 const float* __restrict__ bias0, const float* __restrict__ bias1,
                 const float* __restrict__ bias2,
                 unsigned short* __restrict__ out0, unsigned short* __restrict__ out1,
                 unsigned short* __restrict__ out2,
                 const int* __restrict__ lbp, int K, int Nn)
{
    __shared__ unsigned short As[64][40];        // [m][k]; 40*2=80 B stride (16-B mult)
    __shared__ unsigned short Bs[NB][64][40];    // [n][k] transposed

    const int tid  = threadIdx.x;
    const int m0   = blockIdx.y * 64;
    const int n0   = blockIdx.x * 64;
    const int lane = tid & 63;
    const int wave = tid >> 6;
    const int wr   = (wave >> 1) * 32;
    const int wc   = (wave & 1) * 32;
    const int lm   = lane & 15;
    const int quad = lane >> 4;

    f32x4 acc[NB][2][2];
    const f32x4 zero = {0.f, 0.f, 0.f, 0.f};
    #pragma unroll
    for (int a = 0; a < NB; ++a)
        for (int i = 0; i < 2; ++i)
            for (int j = 0; j < 2; ++j) acc[a][i][j] = zero;

    const float* Af = (const float*)Ap;
    const unsigned short* Ab = (const unsigned short*)Ap;
    const float* Bmats[3] = {Bm0, Bm1, Bm2};

    for (int k0 = 0; k0 < K; k0 += 32) {
        // ---- stage A tile (64 m x 32 k) ----
        #pragma unroll
        for (int it = 0; it < 2; ++it) {
            int cidx = tid + it * 256;          // 512 chunks of 4 elems
            int row  = cidx >> 3;
            int c4   = (cidx & 7) << 2;
            if (!ABF16) {
                float4 v = *(const float4*)(Af + (size_t)(m0 + row) * K + k0 + c4);
                ushort4 o;
                o.x = f2bf(v.x); o.y = f2bf(v.y); o.z = f2bf(v.z); o.w = f2bf(v.w);
                *(ushort4*)&As[row][c4] = o;
            } else {
                ushort4 v = *(const ushort4*)(Ab + (size_t)(m0 + row) * K + k0 + c4);
                *(ushort4*)&As[row][c4] = v;
            }
        }
        // ---- stage B tile(s) (32 k x 64 n) transposed into [n][k] ----
        #pragma unroll
        for (int mat = 0; mat < NB; ++mat) {
            const float* Bp = Bmats[mat];
            #pragma unroll
            for (int it = 0; it < 2; ++it) {
                int cidx = tid + it * 256;
                int krow = cidx >> 4;
                int c4   = (cidx & 15) << 2;
                float4 v = *(const float4*)(Bp + (size_t)(k0 + krow) * Nn + n0 + c4);
                Bs[mat][c4 + 0][krow] = f2bf(v.x);
                Bs[mat][c4 + 1][krow] = f2bf(v.y);
                Bs[mat][c4 + 2][krow] = f2bf(v.z);
                Bs[mat][c4 + 3][krow] = f2bf(v.w);
            }
        }
        __syncthreads();

        bf16x8 a0 = *(const bf16x8*)&As[wr + lm][quad * 8];
        bf16x8 a1 = *(const bf16x8*)&As[wr + 16 + lm][quad * 8];
        #pragma unroll
        for (int mat = 0; mat < NB; ++mat) {
            #pragma unroll
            for (int ni = 0; ni < 2; ++ni) {
                bf16x8 b = *(const bf16x8*)&Bs[mat][wc + ni * 16 + lm][quad * 8];
                acc[mat][0][ni] = __builtin_amdgcn_mfma_f32_16x16x32_bf16(a0, b, acc[mat][0][ni], 0, 0, 0);
                acc[mat][1][ni] = __builtin_amdgcn_mfma_f32_16x16x32_bf16(a1, b, acc[mat][1][ni], 0, 0, 0);
            }
        }
        __syncthreads();
    }

    // C/D: row=(lane>>4)*4+r, col=lane&15 (m89-verified)
    float lbv = 0.f;
    if constexpr (MODE == 1) lbv = (float)(*lbp);

    #pragma unroll
    for (int mi = 0; mi < 2; ++mi) {
        #pragma unroll
        for (int ni = 0; ni < 2; ++ni) {
            #pragma unroll
            for (int r = 0; r < 4; ++r) {
                int row = m0 + wr + mi * 16 + quad * 4 + r;
                int col = n0 + wc + ni * 16 + lm;
                size_t oidx = (size_t)row * Nn + col;
                if constexpr (MODE == 0) {
                    out0[oidx] = f2bf(acc[0][mi][ni][r] + bias0[col]);
                } else if constexpr (MODE == 1) {
                    float iv = acc[0][mi][ni][r] + bias0[col]; iv = iv * sigm(iv);
                    float fv = sigm(acc[1][mi][ni][r] + bias1[col]);
                    float gv = sigm(acc[2][mi][ni][r] + bias2[col]);
                    float lamv = lbv + (1.f - lbv) * fv;
                    float uv = (1.f - lamv) * iv;
                    out0[oidx] = f2bf(lamv);
                    out1[oidx] = f2bf(uv);
                    out2[oidx] = f2bf(gv);
                } else { // MODE 2
                    float s = acc[0][mi][ni][r] + bias0[col]; s = s * sigm(s);
                    float t = acc[1][mi][ni][r] + bias1[col];
                    out0[oidx] = f2bf(s * t);
                }
            }
        }
    }
}

// ---------------------------------------------------------------------------
// Scan pass 1: per (b,chunk,d) aggregates in one ascending pass:
// A = prod(lam), Vf = fwd scan end value, Vr = rev scan start value.
// ---------------------------------------------------------------------------
__global__ __launch_bounds__(512)
void scan_agg(const unsigned short* __restrict__ lam, const unsigned short* __restrict__ u,
              float* __restrict__ Aarr, float* __restrict__ Vf, float* __restrict__ Vr)
{
    int bc = blockIdx.x;             // b*CC + c
    int b = bc >> 5, c = bc & 31;
    int d = threadIdx.x;
    size_t base = ((size_t)b * NN + c * LLEN) * DD + d;
    float A = 1.f, vf = 0.f, vr = 0.f;
    for (int t = 0; t < LLEN; ++t) {
        float lv = bf2f(lam[base + (size_t)t * DD]);
        float uv = bf2f(u[base + (size_t)t * DD]);
        vf = lv * vf + uv;
        vr += uv * A;
        A *= lv;
    }
    size_t o = (size_t)bc * DD + d;
    Aarr[o] = A; Vf[o] = vf; Vr[o] = vr;
}

// Scan pass 2: sequential cross-chunk combine per (b,d) -> carries.
__global__ __launch_bounds__(256)
void scan_comb(const float* __restrict__ Aarr, const float* __restrict__ Vf,
               const float* __restrict__ Vr, float* __restrict__ cf, float* __restrict__ cr)
{
    int g = blockIdx.x * 256 + threadIdx.x;  // 0..Bch*DD-1
    int b = g >> 9, d = g & 511;
    float S = 0.f;
    for (int c = 0; c < CC; ++c) {
        size_t o = (size_t)(b * CC + c) * DD + d;
        cf[o] = S;
        S = Vf[o] + Aarr[o] * S;
    }
    S = 0.f;
    for (int c = CC - 1; c >= 0; --c) {
        size_t o = (size_t)(b * CC + c) * DD + d;
        cr[o] = S;
        S = Vr[o] + Aarr[o] * S;
    }
}

// Scan pass 3: replay chunk with carries; fwd partials in 64 regs; h = hf+hr (fp32).
__global__ __launch_bounds__(256)
void scan_final(const unsigned short* __restrict__ lam, const unsigned short* __restrict__ u,
                const float* __restrict__ cf, const float* __restrict__ cr,
                float* __restrict__ h)
{
    int bid = blockIdx.x;            // b*64 + c*2 + dhalf
    int dh = bid & 1, c = (bid >> 1) & 31, b = bid >> 6;
    int d = dh * 256 + threadIdx.x;
    size_t base = ((size_t)b * NN + c * LLEN) * DD + d;
    size_t co   = (size_t)(b * CC + c) * DD + d;

    float hbuf[LLEN];
    float hf = cf[co];
    #pragma unroll
    for (int t = 0; t < LLEN; ++t) {
        float lv = bf2f(lam[base + (size_t)t * DD]);
        float uv = bf2f(u[base + (size_t)t * DD]);
        hf = lv * hf + uv;
        hbuf[t] = hf;
    }
    float hr = cr[co];
    #pragma unroll
    for (int t = LLEN - 1; t >= 0; --t) {
        float lv = bf2f(lam[base + (size_t)t * DD]);
        float uv = bf2f(u[base + (size_t)t * DD]);
        hr = lv * hr + uv;
        h[base + (size_t)t * DD] = hbuf[t] + hr;
    }
}

// hg = h * rsqrt(mean(h^2)+1e-6) * g   (bf16 out, in-place over g is safe)
__global__ __launch_bounds__(256)
void rms_mul(const float* __restrict__ h, const unsigned short* __restrict__ g,
             unsigned short* __restrict__ hg)
{
    int row = blockIdx.x;
    size_t base = (size_t)row * DD;
    int tid = threadIdx.x, col = tid * 2;
    float2 v = *(const float2*)&h[base + col];
    float ss = v.x * v.x + v.y * v.y;
    #pragma unroll
    for (int off = 32; off > 0; off >>= 1) ss += __shfl_down(ss, off);
    __shared__ float ps[4];
    __shared__ float scale_s;
    if ((tid & 63) == 0) ps[tid >> 6] = ss;
    __syncthreads();
    if (tid == 0) scale_s = rsqrtf((ps[0] + ps[1] + ps[2] + ps[3]) * (1.f / DD) + 1e-6f);
    __syncthreads();
    float sc = scale_s;
    ushort2 gv = *(const ushort2*)&g[base + col];
    ushort2 o;
    o.x = f2bf(v.x * sc * bf2f(gv.x));
    o.y = f2bf(v.y * sc * bf2f(gv.y));
    *(ushort2*)&hg[base + col] = o;
}

// out = xin + layernorm(y)*gam + bet  (y bf16; xin/out fp32; xin==out safe)
__global__ __launch_bounds__(256)
void add_ln(const float* __restrict__ xin, const unsigned short* __restrict__ y,
            const float* __restrict__ gam, const float* __restrict__ bet,
            float* __restrict__ out)
{
    int row = blockIdx.x;
    size_t base = (size_t)row * DD;
    int tid = threadIdx.x, col = tid * 2;
    ushort2 yv = *(const ushort2*)&y[base + col];
    float vx = bf2f(yv.x), vy = bf2f(yv.y);
    float s = vx + vy;
    float ss = vx * vx + vy * vy;
    #pragma unroll
    for (int off = 32; off > 0; off >>= 1) {
        s  += __shfl_down(s, off);
        ss += __shfl_down(ss, off);
    }
    __shared__ float ps[8];
    __shared__ float stats[2];
    if ((tid & 63) == 0) { ps[tid >> 6] = s; ps[4 + (tid >> 6)] = ss; }
    __syncthreads();
    if (tid == 0) {
        float st  = ps[0] + ps[1] + ps[2] + ps[3];
        float sst = ps[4] + ps[5] + ps[6] + ps[7];
        float mean = st * (1.f / DD);
        float var  = sst * (1.f / DD) - mean * mean;
        stats[0] = mean; stats[1] = rsqrtf(var + 1e-5f);
    }
    __syncthreads();
    float mean = stats[0], inv = stats[1];
    float2 xv = *(const float2*)&xin[base + col];
    float2 gv = *(const float2*)&gam[col];
    float2 bv = *(const float2*)&bet[col];
    float2 o;
    o.x = xv.x + (vx - mean) * inv * gv.x + bv.x;
    o.y = xv.y + (vy - mean) * inv * gv.y + bv.y;
    *(float2*)&out[base + col] = o;
}

extern "C" void kernel_launch(void* const* d_in, const int* in_sizes, int n_in,
                              void* d_out, int out_size, void* d_ws, size_t ws_size,
                              hipStream_t stream)
{
    const float* x   = (const float*)d_in[0];
    const int*   lb  = (const int*)d_in[1];
    const float* Wi  = (const float*)d_in[2];
    const float* bi  = (const float*)d_in[3];
    const float* Wf  = (const float*)d_in[4];
    const float* bfp = (const float*)d_in[5];
    const float* Wg  = (const float*)d_in[6];
    const float* bg  = (const float*)d_in[7];
    const float* Wo  = (const float*)d_in[8];
    const float* bo  = (const float*)d_in[9];
    const float* tng = (const float*)d_in[10];
    const float* tnb = (const float*)d_in[11];
    const float* fng = (const float*)d_in[12];
    const float* fnb = (const float*)d_in[13];
    const float* W1  = (const float*)d_in[14];
    const float* b1  = (const float*)d_in[15];
    const float* W2  = (const float*)d_in[16];
    const float* b2  = (const float*)d_in[17];
    const float* W3  = (const float*)d_in[18];
    const float* b3  = (const float*)d_in[19];

    // ws bytes per batch row: 3 bf16 slabs (NN*DD each) + 5 fp32 aggregates (CC*DD each)
    const size_t perB = (size_t)3 * NN * DD * 2 + (size_t)5 * CC * DD * 4;
    int Bch = 32;
    while (Bch > 1 && (size_t)Bch * perB > ws_size) Bch >>= 1;
    const int nch = BB / Bch;

    const size_t slabE = (size_t)Bch * NN * DD;   // elements per bf16 slab

    for (int ch = 0; ch < nch; ++ch) {
        const size_t r0 = (size_t)ch * Bch * NN;  // first row of this chunk
        const float* xc = x + r0 * DD;
        unsigned short* S0 = (unsigned short*)d_ws;
        unsigned short* S1 = S0 + slabE;
        unsigned short* S2 = S0 + 2 * slabE;
        float* small = (float*)(S0 + 3 * slabE);
        const size_t agg = (size_t)Bch * CC * DD;
        float* Aarr = small;
        float* VfP  = small + agg;
        float* VrP  = small + 2 * agg;
        float* cfP  = small + 3 * agg;
        float* crP  = small + 4 * agg;
        float* hout = (float*)d_out + r0 * DD;    // h -> xr -> final out

        // 1) triple GEMM: x@{Wi,Wf,Wg} -> lam(S0), u(S1), g(S2)
        gemm_kernel<1, 3, false><<<dim3(DD / 64, Bch * NN / 64), 256, 0, stream>>>(
            xc, Wi, Wf, Wg, bi, bfp, bg, S0, S1, S2, lb, DD, DD);
        // 2-4) bidirectional chunked scan -> h (fp32, in d_out region)
        scan_agg<<<Bch * CC, 512, 0, stream>>>(S0, S1, Aarr, VfP, VrP);
        scan_comb<<<(Bch * DD) / 256, 256, 0, stream>>>(Aarr, VfP, VrP, cfP, crP);
        scan_final<<<Bch * CC * 2, 256, 0, stream>>>(S0, S1, cfP, crP, hout);
        // 5) hg = rms_norm(h)*g  (bf16, in place over g in S2)
        rms_mul<<<Bch * NN, 256, 0, stream>>>(hout, S2, S2);
        // 6) y2 = hg@Wo + bo  (bf16 -> S0; lam dead)
        gemm_kernel<0, 1, true><<<dim3(DD / 64, Bch * NN / 64), 256, 0, stream>>>(
            S2, Wo, nullptr, nullptr, bo, nullptr, nullptr, S0, nullptr, nullptr,
            nullptr, DD, DD);
        // 7) xr = x + LN(y2)*tn_g + tn_b  (fp32 -> d_out region; h dead)
        add_ln<<<Bch * NN, 256, 0, stream>>>(xc, S0, tng, tnb, hout);
        // 8) dual GLU GEMM: v = silu(xr@W1+b1)*(xr@W2+b2)  (bf16 -> S0+S1; y2,u dead)
        gemm_kernel<2, 2, false><<<dim3(DGG / 64, Bch * NN / 64), 256, 0, stream>>>(
            hout, W1, W2, nullptr, b1, b2, nullptr, S0, nullptr, nullptr, nullptr, DD, DGG);
        // 9) y4 = v@W3 + b3  (bf16 -> S2; hg dead)
        gemm_kernel<0, 1, true><<<dim3(DD / 64, Bch * NN / 64), 256, 0, stream>>>(
            S0, W3, nullptr, nullptr, b3, nullptr, nullptr, S2, nullptr, nullptr,
            nullptr, DGG, DD);
        // 10) out = xr + LN(y4)*fn_g + fn_b  (fp32, in place in d_out region)
        add_ln<<<Bch * NN, 256, 0, stream>>>(hout, S2, fng, fnb, hout);
    }
}

// Round 3
// 1379.813 us; speedup vs baseline: 1.4833x; 1.4833x over previous
//
#include <hip/hip_runtime.h>
#include <hip/hip_bf16.h>

#define BB 32
#define NN 2048
#define DD 512
#define DGG 1024
#define CC 32          // scan chunks per sequence
#define LLEN 64        // scan chunk length (CC*LLEN == NN)

typedef short bf16x8 __attribute__((ext_vector_type(8)));
typedef float f32x4  __attribute__((ext_vector_type(4)));

__device__ __forceinline__ unsigned short f2bf(float f){
    __hip_bfloat16 h = __float2bfloat16(f);
    return *reinterpret_cast<unsigned short*>(&h);
}
__device__ __forceinline__ float bf2f(unsigned short u){
    unsigned int x = ((unsigned int)u) << 16;
    return __uint_as_float(x);
}
__device__ __forceinline__ float sigm(float x){ return 1.0f/(1.0f + __expf(-x)); }

// ---------------------------------------------------------------------------
// Weight prep: transpose + cast  in[K][N] fp32  ->  out[N][K] bf16.
// 32x32 LDS tile, +1 pad; both global access legs coalesced.
// ---------------------------------------------------------------------------
__global__ __launch_bounds__(256)
void wt_prep(const float* __restrict__ in, unsigned short* __restrict__ out,
             int K, int N)
{
    __shared__ float t[32][33];
    const int tid = threadIdx.x;
    const int r = tid >> 3;            // 0..31
    const int c = (tid & 7) << 2;      // 0,4,..,28
    const int n0 = blockIdx.x * 32;
    const int k0 = blockIdx.y * 32;
    float4 v = *(const float4*)(in + (size_t)(k0 + r) * N + n0 + c);
    t[r][c] = v.x; t[r][c+1] = v.y; t[r][c+2] = v.z; t[r][c+3] = v.w;
    __syncthreads();
    ushort4 o;
    o.x = f2bf(t[c+0][r]); o.y = f2bf(t[c+1][r]);
    o.z = f2bf(t[c+2][r]); o.w = f2bf(t[c+3][r]);
    *(ushort4*)(out + (size_t)(n0 + r) * K + k0 + c) = o;
}

// ---------------------------------------------------------------------------
// 64x64-tile bf16 MFMA GEMM.  B operands are pre-transposed bf16 [Nn][K].
// All outputs bf16.
//   MODE 0: out0 = A@B0 + bias0
//   MODE 1: triple i,f,g -> lam, u, g
//   MODE 2: dual GLU -> v = silu(A@B0+b0) * (A@B1+b1)
// ABF16: A operand already bf16 (else fp32, cast during staging).
// ---------------------------------------------------------------------------
template<int MODE, int NB, bool ABF16>
__global__ __launch_bounds__(256)
void gemm_kernel(const void* __restrict__ Ap,
                 const unsigned short* __restrict__ Bt0,
                 const unsigned short* __restrict__ Bt1,
                 const unsigned short* __restrict__ Bt2,
                 const float* __restrict__ bias0, const float* __restrict__ bias1,
                 const float* __restrict__ bias2,
                 unsigned short* __restrict__ out0, unsigned short* __restrict__ out1,
                 unsigned short* __restrict__ out2,
                 const int* __restrict__ lbp, int K, int Nn)
{
    __shared__ unsigned short As[64][40];        // [m][k]; row stride 80 B (16-B mult)
    __shared__ unsigned short Bs[NB][64][40];    // [n][k]

    const int tid  = threadIdx.x;
    const int m0   = blockIdx.y * 64;
    const int n0   = blockIdx.x * 64;
    const int lane = tid & 63;
    const int wave = tid >> 6;
    const int wr   = (wave >> 1) * 32;
    const int wc   = (wave & 1) * 32;
    const int lm   = lane & 15;
    const int quad = lane >> 4;

    f32x4 acc[NB][2][2];
    const f32x4 zero = {0.f, 0.f, 0.f, 0.f};
    #pragma unroll
    for (int a = 0; a < NB; ++a)
        for (int i = 0; i < 2; ++i)
            for (int j = 0; j < 2; ++j) acc[a][i][j] = zero;

    const float* Af = (const float*)Ap;
    const unsigned short* Ab = (const unsigned short*)Ap;
    const unsigned short* Bmats[3] = {Bt0, Bt1, Bt2};

    // staging thread mapping (16B chunks): 256 chunks of 8 shorts
    const int srow = tid >> 2;          // 0..63
    const int sc8  = (tid & 3) << 3;    // 0,8,16,24

    for (int k0 = 0; k0 < K; k0 += 32) {
        // ---- stage A tile (64 m x 32 k) ----
        if (!ABF16) {
            #pragma unroll
            for (int it = 0; it < 2; ++it) {
                int cidx = tid + it * 256;          // 512 chunks of 4 elems
                int row  = cidx >> 3;
                int c4   = (cidx & 7) << 2;
                float4 v = *(const float4*)(Af + (size_t)(m0 + row) * K + k0 + c4);
                ushort4 o;
                o.x = f2bf(v.x); o.y = f2bf(v.y); o.z = f2bf(v.z); o.w = f2bf(v.w);
                *(ushort4*)&As[row][c4] = o;
            }
        } else {
            bf16x8 v = *(const bf16x8*)(Ab + (size_t)(m0 + srow) * K + k0 + sc8);
            *(bf16x8*)&As[srow][sc8] = v;
        }
        // ---- stage B tile(s): contiguous along k, 16B loads + b128 LDS writes ----
        #pragma unroll
        for (int mat = 0; mat < NB; ++mat) {
            bf16x8 v = *(const bf16x8*)(Bmats[mat] + (size_t)(n0 + srow) * K + k0 + sc8);
            *(bf16x8*)&Bs[mat][srow][sc8] = v;
        }
        __syncthreads();

        bf16x8 a0 = *(const bf16x8*)&As[wr + lm][quad * 8];
        bf16x8 a1 = *(const bf16x8*)&As[wr + 16 + lm][quad * 8];
        #pragma unroll
        for (int mat = 0; mat < NB; ++mat) {
            #pragma unroll
            for (int ni = 0; ni < 2; ++ni) {
                bf16x8 b = *(const bf16x8*)&Bs[mat][wc + ni * 16 + lm][quad * 8];
                acc[mat][0][ni] = __builtin_amdgcn_mfma_f32_16x16x32_bf16(a0, b, acc[mat][0][ni], 0, 0, 0);
                acc[mat][1][ni] = __builtin_amdgcn_mfma_f32_16x16x32_bf16(a1, b, acc[mat][1][ni], 0, 0, 0);
            }
        }
        __syncthreads();
    }

    // C/D: row=(lane>>4)*4+r, col=lane&15 (m89-verified)
    float lbv = 0.f;
    if constexpr (MODE == 1) lbv = (float)(*lbp);

    #pragma unroll
    for (int mi = 0; mi < 2; ++mi) {
        #pragma unroll
        for (int ni = 0; ni < 2; ++ni) {
            #pragma unroll
            for (int r = 0; r < 4; ++r) {
                int row = m0 + wr + mi * 16 + quad * 4 + r;
                int col = n0 + wc + ni * 16 + lm;
                size_t oidx = (size_t)row * Nn + col;
                if constexpr (MODE == 0) {
                    out0[oidx] = f2bf(acc[0][mi][ni][r] + bias0[col]);
                } else if constexpr (MODE == 1) {
                    float iv = acc[0][mi][ni][r] + bias0[col]; iv = iv * sigm(iv);
                    float fv = sigm(acc[1][mi][ni][r] + bias1[col]);
                    float gv = sigm(acc[2][mi][ni][r] + bias2[col]);
                    float lamv = lbv + (1.f - lbv) * fv;
                    float uv = (1.f - lamv) * iv;
                    out0[oidx] = f2bf(lamv);
                    out1[oidx] = f2bf(uv);
                    out2[oidx] = f2bf(gv);
                } else { // MODE 2
                    float s = acc[0][mi][ni][r] + bias0[col]; s = s * sigm(s);
                    float t = acc[1][mi][ni][r] + bias1[col];
                    out0[oidx] = f2bf(s * t);
                }
            }
        }
    }
}

// ---------------------------------------------------------------------------
// Scan pass 1: per (b,chunk,d) aggregates in one ascending pass:
// A = prod(lam), Vf = fwd scan end value, Vr = rev scan start value.
// ---------------------------------------------------------------------------
__global__ __launch_bounds__(512)
void scan_agg(const unsigned short* __restrict__ lam, const unsigned short* __restrict__ u,
              float* __restrict__ Aarr, float* __restrict__ Vf, float* __restrict__ Vr)
{
    int bc = blockIdx.x;             // b*CC + c
    int b = bc >> 5, c = bc & 31;
    int d = threadIdx.x;
    size_t base = ((size_t)b * NN + c * LLEN) * DD + d;
    float A = 1.f, vf = 0.f, vr = 0.f;
    for (int t = 0; t < LLEN; ++t) {
        float lv = bf2f(lam[base + (size_t)t * DD]);
        float uv = bf2f(u[base + (size_t)t * DD]);
        vf = lv * vf + uv;
        vr += uv * A;
        A *= lv;
    }
    size_t o = (size_t)bc * DD + d;
    Aarr[o] = A; Vf[o] = vf; Vr[o] = vr;
}

// Scan pass 2: sequential cross-chunk combine per (b,d) -> carries.
__global__ __launch_bounds__(256)
void scan_comb(const float* __restrict__ Aarr, const float* __restrict__ Vf,
               const float* __restrict__ Vr, float* __restrict__ cf, float* __restrict__ cr)
{
    int g = blockIdx.x * 256 + threadIdx.x;  // 0..Bch*DD-1
    int b = g >> 9, d = g & 511;
    float S = 0.f;
    for (int c = 0; c < CC; ++c) {
        size_t o = (size_t)(b * CC + c) * DD + d;
        cf[o] = S;
        S = Vf[o] + Aarr[o] * S;
    }
    S = 0.f;
    for (int c = CC - 1; c >= 0; --c) {
        size_t o = (size_t)(b * CC + c) * DD + d;
        cr[o] = S;
        S = Vr[o] + Aarr[o] * S;
    }
}

// Scan pass 3: replay chunk with carries; fwd partials in 64 regs; h = hf+hr (fp32).
__global__ __launch_bounds__(256)
void scan_final(const unsigned short* __restrict__ lam, const unsigned short* __restrict__ u,
                const float* __restrict__ cf, const float* __restrict__ cr,
                float* __restrict__ h)
{
    int bid = blockIdx.x;            // b*64 + c*2 + dhalf
    int dh = bid & 1, c = (bid >> 1) & 31, b = bid >> 6;
    int d = dh * 256 + threadIdx.x;
    size_t base = ((size_t)b * NN + c * LLEN) * DD + d;
    size_t co   = (size_t)(b * CC + c) * DD + d;

    float hbuf[LLEN];
    float hf = cf[co];
    #pragma unroll
    for (int t = 0; t < LLEN; ++t) {
        float lv = bf2f(lam[base + (size_t)t * DD]);
        float uv = bf2f(u[base + (size_t)t * DD]);
        hf = lv * hf + uv;
        hbuf[t] = hf;
    }
    float hr = cr[co];
    #pragma unroll
    for (int t = LLEN - 1; t >= 0; --t) {
        float lv = bf2f(lam[base + (size_t)t * DD]);
        float uv = bf2f(u[base + (size_t)t * DD]);
        hr = lv * hr + uv;
        h[base + (size_t)t * DD] = hbuf[t] + hr;
    }
}

// hg = h * rsqrt(mean(h^2)+1e-6) * g   (bf16 out, in-place over g is safe)
__global__ __launch_bounds__(256)
void rms_mul(const float* __restrict__ h, const unsigned short* __restrict__ g,
             unsigned short* __restrict__ hg)
{
    int row = blockIdx.x;
    size_t base = (size_t)row * DD;
    int tid = threadIdx.x, col = tid * 2;
    float2 v = *(const float2*)&h[base + col];
    float ss = v.x * v.x + v.y * v.y;
    #pragma unroll
    for (int off = 32; off > 0; off >>= 1) ss += __shfl_down(ss, off);
    __shared__ float ps[4];
    __shared__ float scale_s;
    if ((tid & 63) == 0) ps[tid >> 6] = ss;
    __syncthreads();
    if (tid == 0) scale_s = rsqrtf((ps[0] + ps[1] + ps[2] + ps[3]) * (1.f / DD) + 1e-6f);
    __syncthreads();
    float sc = scale_s;
    ushort2 gv = *(const ushort2*)&g[base + col];
    ushort2 o;
    o.x = f2bf(v.x * sc * bf2f(gv.x));
    o.y = f2bf(v.y * sc * bf2f(gv.y));
    *(ushort2*)&hg[base + col] = o;
}

// out = xin + layernorm(y)*gam + bet  (y bf16; xin/out fp32; xin==out safe)
__global__ __launch_bounds__(256)
void add_ln(const float* __restrict__ xin, const unsigned short* __restrict__ y,
            const float* __restrict__ gam, const float* __restrict__ bet,
            float* __restrict__ out)
{
    int row = blockIdx.x;
    size_t base = (size_t)row * DD;
    int tid = threadIdx.x, col = tid * 2;
    ushort2 yv = *(const ushort2*)&y[base + col];
    float vx = bf2f(yv.x), vy = bf2f(yv.y);
    float s = vx + vy;
    float ss = vx * vx + vy * vy;
    #pragma unroll
    for (int off = 32; off > 0; off >>= 1) {
        s  += __shfl_down(s, off);
        ss += __shfl_down(ss, off);
    }
    __shared__ float ps[8];
    __shared__ float stats[2];
    if ((tid & 63) == 0) { ps[tid >> 6] = s; ps[4 + (tid >> 6)] = ss; }
    __syncthreads();
    if (tid == 0) {
        float st  = ps[0] + ps[1] + ps[2] + ps[3];
        float sst = ps[4] + ps[5] + ps[6] + ps[7];
        float mean = st * (1.f / DD);
        float var  = sst * (1.f / DD) - mean * mean;
        stats[0] = mean; stats[1] = rsqrtf(var + 1e-5f);
    }
    __syncthreads();
    float mean = stats[0], inv = stats[1];
    float2 xv = *(const float2*)&xin[base + col];
    float2 gv = *(const float2*)&gam[col];
    float2 bv = *(const float2*)&bet[col];
    float2 o;
    o.x = xv.x + (vx - mean) * inv * gv.x + bv.x;
    o.y = xv.y + (vy - mean) * inv * gv.y + bv.y;
    *(float2*)&out[base + col] = o;
}

extern "C" void kernel_launch(void* const* d_in, const int* in_sizes, int n_in,
                              void* d_out, int out_size, void* d_ws, size_t ws_size,
                              hipStream_t stream)
{
    const float* x   = (const float*)d_in[0];
    const int*   lb  = (const int*)d_in[1];
    const float* Wi  = (const float*)d_in[2];
    const float* bi  = (const float*)d_in[3];
    const float* Wf  = (const float*)d_in[4];
    const float* bfp = (const float*)d_in[5];
    const float* Wg  = (const float*)d_in[6];
    const float* bg  = (const float*)d_in[7];
    const float* Wo  = (const float*)d_in[8];
    const float* bo  = (const float*)d_in[9];
    const float* tng = (const float*)d_in[10];
    const float* tnb = (const float*)d_in[11];
    const float* fng = (const float*)d_in[12];
    const float* fnb = (const float*)d_in[13];
    const float* W1  = (const float*)d_in[14];
    const float* b1  = (const float*)d_in[15];
    const float* W2  = (const float*)d_in[16];
    const float* b2  = (const float*)d_in[17];
    const float* W3  = (const float*)d_in[18];
    const float* b3  = (const float*)d_in[19];

    // ---- ws layout: [bf16 transposed weights | 3 bf16 slabs | fp32 aggregates] ----
    unsigned short* wbase = (unsigned short*)d_ws;
    unsigned short* WiT = wbase;                  // 512x512
    unsigned short* WfT = WiT + 262144;
    unsigned short* WgT = WfT + 262144;
    unsigned short* WoT = WgT + 262144;
    unsigned short* W1T = WoT + 262144;           // 1024x512
    unsigned short* W2T = W1T + 524288;
    unsigned short* W3T = W2T + 524288;           // 512x1024
    const size_t WTOT = 4 * 262144 + 3 * 524288;  // 2,621,440 shorts (5 MiB)

    wt_prep<<<dim3(16, 16), 256, 0, stream>>>(Wi, WiT, 512, 512);
    wt_prep<<<dim3(16, 16), 256, 0, stream>>>(Wf, WfT, 512, 512);
    wt_prep<<<dim3(16, 16), 256, 0, stream>>>(Wg, WgT, 512, 512);
    wt_prep<<<dim3(16, 16), 256, 0, stream>>>(Wo, WoT, 512, 512);
    wt_prep<<<dim3(32, 16), 256, 0, stream>>>(W1, W1T, 512, 1024);
    wt_prep<<<dim3(32, 16), 256, 0, stream>>>(W2, W2T, 512, 1024);
    wt_prep<<<dim3(16, 32), 256, 0, stream>>>(W3, W3T, 1024, 512);

    // per batch row: 3 bf16 slabs (NN*DD) + 5 fp32 aggregates (CC*DD)
    const size_t perB = (size_t)3 * NN * DD * 2 + (size_t)5 * CC * DD * 4;
    int Bch = 32;
    while (Bch > 1 && WTOT * 2 + (size_t)Bch * perB > ws_size) Bch >>= 1;
    const int nch = BB / Bch;

    const size_t slabE = (size_t)Bch * NN * DD;   // elements per bf16 slab

    for (int ch = 0; ch < nch; ++ch) {
        const size_t r0 = (size_t)ch * Bch * NN;  // first row of this chunk
        const float* xc = x + r0 * DD;
        unsigned short* S0 = wbase + WTOT;
        unsigned short* S1 = S0 + slabE;
        unsigned short* S2 = S0 + 2 * slabE;
        float* small = (float*)(S0 + 3 * slabE);
        const size_t agg = (size_t)Bch * CC * DD;
        float* Aarr = small;
        float* VfP  = small + agg;
        float* VrP  = small + 2 * agg;
        float* cfP  = small + 3 * agg;
        float* crP  = small + 4 * agg;
        float* hout = (float*)d_out + r0 * DD;    // h -> xr -> final out

        // 1) triple GEMM: x@{Wi,Wf,Wg} -> lam(S0), u(S1), g(S2)
        gemm_kernel<1, 3, false><<<dim3(DD / 64, Bch * NN / 64), 256, 0, stream>>>(
            xc, WiT, WfT, WgT, bi, bfp, bg, S0, S1, S2, lb, DD, DD);
        // 2-4) bidirectional chunked scan -> h (fp32, in d_out region)
        scan_agg<<<Bch * CC, 512, 0, stream>>>(S0, S1, Aarr, VfP, VrP);
        scan_comb<<<(Bch * DD) / 256, 256, 0, stream>>>(Aarr, VfP, VrP, cfP, crP);
        scan_final<<<Bch * CC * 2, 256, 0, stream>>>(S0, S1, cfP, crP, hout);
        // 5) hg = rms_norm(h)*g  (bf16, in place over g in S2)
        rms_mul<<<Bch * NN, 256, 0, stream>>>(hout, S2, S2);
        // 6) y2 = hg@Wo + bo  (bf16 -> S0; lam dead)
        gemm_kernel<0, 1, true><<<dim3(DD / 64, Bch * NN / 64), 256, 0, stream>>>(
            S2, WoT, nullptr, nullptr, bo, nullptr, nullptr, S0, nullptr, nullptr,
            nullptr, DD, DD);
        // 7) xr = x + LN(y2)*tn_g + tn_b  (fp32 -> d_out region; h dead)
        add_ln<<<Bch * NN, 256, 0, stream>>>(xc, S0, tng, tnb, hout);
        // 8) dual GLU GEMM: v = silu(xr@W1+b1)*(xr@W2+b2)  (bf16 -> S0; y2 dead)
        gemm_kernel<2, 2, false><<<dim3(DGG / 64, Bch * NN / 64), 256, 0, stream>>>(
            hout, W1T, W2T, nullptr, b1, b2, nullptr, S0, nullptr, nullptr, nullptr, DD, DGG);
        // 9) y4 = v@W3 + b3  (bf16 -> S2; hg dead)
        gemm_kernel<0, 1, true><<<dim3(DD / 64, Bch * NN / 64), 256, 0, stream>>>(
            S0, W3T, nullptr, nullptr, b3, nullptr, nullptr, S2, nullptr, nullptr,
            nullptr, DGG, DD);
        // 10) out = xr + LN(y4)*fn_g + fn_b  (fp32, in place in d_out region)
        add_ln<<<Bch * NN, 256, 0, stream>>>(hout, S2, fng, fnb, hout);
    }
}

// Round 4
// 1291.448 us; speedup vs baseline: 1.5848x; 1.0684x over previous
//
#include <hip/hip_runtime.h>
#include <hip/hip_bf16.h>

#define BB 32
#define NN 2048
#define DD 512
#define DGG 1024
#define CC 32          // scan chunks per sequence
#define LLEN 64        // scan chunk length (CC*LLEN == NN)

typedef short bf16x8 __attribute__((ext_vector_type(8)));
typedef float f32x4  __attribute__((ext_vector_type(4)));

__device__ __forceinline__ unsigned short f2bf(float f){
    __hip_bfloat16 h = __float2bfloat16(f);
    return *reinterpret_cast<unsigned short*>(&h);
}
__device__ __forceinline__ float bf2f(unsigned short u){
    unsigned int x = ((unsigned int)u) << 16;
    return __uint_as_float(x);
}
__device__ __forceinline__ float sigm(float x){ return 1.0f/(1.0f + __expf(-x)); }

// async global->LDS, 16B per lane; LDS dest = wave-uniform base + lane*16 (m97/m104)
__device__ __forceinline__ void gl_lds16(const unsigned short* g, unsigned short* l){
    __builtin_amdgcn_global_load_lds(
        (const __attribute__((address_space(1))) unsigned int*)g,
        (__attribute__((address_space(3))) unsigned int*)l, 16, 0, 0);
}

// ---------------------------------------------------------------------------
// Weight prep: transpose + cast  in[K][N] fp32  ->  out[N][K] bf16.
// ---------------------------------------------------------------------------
__global__ __launch_bounds__(256)
void wt_prep(const float* __restrict__ in, unsigned short* __restrict__ out,
             int K, int N)
{
    __shared__ float t[32][33];
    const int tid = threadIdx.x;
    const int r = tid >> 3;            // 0..31
    const int c = (tid & 7) << 2;      // 0,4,..,28
    const int n0 = blockIdx.x * 32;
    const int k0 = blockIdx.y * 32;
    float4 v = *(const float4*)(in + (size_t)(k0 + r) * N + n0 + c);
    t[r][c] = v.x; t[r][c+1] = v.y; t[r][c+2] = v.z; t[r][c+3] = v.w;
    __syncthreads();
    ushort4 o;
    o.x = f2bf(t[c+0][r]); o.y = f2bf(t[c+1][r]);
    o.z = f2bf(t[c+2][r]); o.w = f2bf(t[c+3][r]);
    *(ushort4*)(out + (size_t)(n0 + r) * K + k0 + c) = o;
}

// fp32 -> bf16 cast, 4 elems/thread
__global__ __launch_bounds__(256)
void cast_bf16(const float* __restrict__ in, unsigned short* __restrict__ out)
{
    size_t i = ((size_t)blockIdx.x * 256 + threadIdx.x) * 4;
    float4 v = *(const float4*)(in + i);
    ushort4 o;
    o.x = f2bf(v.x); o.y = f2bf(v.y); o.z = f2bf(v.z); o.w = f2bf(v.w);
    *(ushort4*)(out + i) = o;
}

// ---------------------------------------------------------------------------
// m97-style 128x128 bf16 MFMA GEMM.  A[M][K] bf16, Bt[Nn][K] bf16 (pre-T).
// 4 waves, each 64x64 (4x4 16x16x32 MFMA).  global_load_lds staging.
//   MODE 0: out0 = A@B + bias
//   MODE 1: out0 = silu(A@B + bias)
//   MODE 2: out0 = sigmoid(A@B + bias)
//   MODE 3: fv=sigm(+bias); lam=lb+(1-lb)*fv -> out0; u=(1-lam)*staged -> out1
//   MODE 4: out0 = staged * (A@B + bias)
// staged may alias out0/out1 (same-thread read-then-write per element).
// ---------------------------------------------------------------------------
template<int MODE>
__global__ __launch_bounds__(256)
void gemm128(const unsigned short* __restrict__ A,
             const unsigned short* __restrict__ Bt,
             const float* __restrict__ bias,
             const unsigned short* __restrict__ staged,
             unsigned short* __restrict__ out0,
             unsigned short* __restrict__ out1,
             const int* __restrict__ lbp, int K, int Nn)
{
    __shared__ unsigned short As[128 * 32];   // [m][k] row-major, no pad (gl_lds)
    __shared__ unsigned short Bs[128 * 32];   // [n][k]

    const int tid  = threadIdx.x;
    const int wave = tid >> 6;
    const int lane = tid & 63;
    const int m0   = blockIdx.y * 128;
    const int n0   = blockIdx.x * 128;
    const int wr   = (wave >> 1) * 64;
    const int wc   = (wave & 1) * 64;
    const int lm   = lane & 15;
    const int quad = lane >> 4;

    f32x4 acc[4][4];
    const f32x4 zero = {0.f, 0.f, 0.f, 0.f};
    #pragma unroll
    for (int i = 0; i < 4; ++i)
        for (int j = 0; j < 4; ++j) acc[i][j] = zero;

    // staging: wave w loads rows w*32..w*32+31 of each tile (2 gl_lds each of
    // 16 rows: 64 lanes x 16B = 16 rows x 64B).  lane -> row=lane>>2, k=(lane&3)*8
    const int srow = wave * 32 + (lane >> 2);
    const int skof = (lane & 3) << 3;
    const unsigned short* ga0 = A  + (size_t)(m0 + srow) * K + skof;
    const unsigned short* ga1 = ga0 + (size_t)16 * K;
    const unsigned short* gb0 = Bt + (size_t)(n0 + srow) * K + skof;
    const unsigned short* gb1 = gb0 + (size_t)16 * K;
    unsigned short* la0 = &As[(wave * 32) * 32];
    unsigned short* la1 = &As[(wave * 32 + 16) * 32];
    unsigned short* lb0 = &Bs[(wave * 32) * 32];
    unsigned short* lb1 = &Bs[(wave * 32 + 16) * 32];

    for (int k0 = 0; k0 < K; k0 += 32) {
        gl_lds16(ga0, la0); gl_lds16(ga1, la1);
        gl_lds16(gb0, lb0); gl_lds16(gb1, lb1);
        ga0 += 32; ga1 += 32; gb0 += 32; gb1 += 32;
        __syncthreads();

        bf16x8 a[4], b[4];
        #pragma unroll
        for (int mi = 0; mi < 4; ++mi)
            a[mi] = *(const bf16x8*)&As[(wr + mi * 16 + lm) * 32 + quad * 8];
        #pragma unroll
        for (int ni = 0; ni < 4; ++ni)
            b[ni] = *(const bf16x8*)&Bs[(wc + ni * 16 + lm) * 32 + quad * 8];
        #pragma unroll
        for (int mi = 0; mi < 4; ++mi)
            #pragma unroll
            for (int ni = 0; ni < 4; ++ni)
                acc[mi][ni] = __builtin_amdgcn_mfma_f32_16x16x32_bf16(a[mi], b[ni], acc[mi][ni], 0, 0, 0);
        __syncthreads();
    }

    // C/D: row=(lane>>4)*4+r, col=lane&15 (m89-verified)
    float lbv = 0.f;
    if constexpr (MODE == 3) lbv = (float)(*lbp);

    #pragma unroll
    for (int mi = 0; mi < 4; ++mi) {
        #pragma unroll
        for (int ni = 0; ni < 4; ++ni) {
            int col = n0 + wc + ni * 16 + lm;
            float bcol = bias[col];
            #pragma unroll
            for (int r = 0; r < 4; ++r) {
                int row = m0 + wr + mi * 16 + quad * 4 + r;
                size_t oidx = (size_t)row * Nn + col;
                float v = acc[mi][ni][r] + bcol;
                if constexpr (MODE == 0) {
                    out0[oidx] = f2bf(v);
                } else if constexpr (MODE == 1) {
                    out0[oidx] = f2bf(v * sigm(v));
                } else if constexpr (MODE == 2) {
                    out0[oidx] = f2bf(sigm(v));
                } else if constexpr (MODE == 3) {
                    float fv = sigm(v);
                    float lamv = lbv + (1.f - lbv) * fv;
                    float si = bf2f(staged[oidx]);
                    out0[oidx] = f2bf(lamv);
                    out1[oidx] = f2bf((1.f - lamv) * si);
                } else { // MODE 4
                    out0[oidx] = f2bf(bf2f(staged[oidx]) * v);
                }
            }
        }
    }
}

// ---------------------------------------------------------------------------
// Scan pass 1: per (b,chunk,d) aggregates in one ascending pass.
// ---------------------------------------------------------------------------
__global__ __launch_bounds__(512)
void scan_agg(const unsigned short* __restrict__ lam, const unsigned short* __restrict__ u,
              float* __restrict__ Aarr, float* __restrict__ Vf, float* __restrict__ Vr)
{
    int bc = blockIdx.x;             // b*CC + c
    int b = bc >> 5, c = bc & 31;
    int d = threadIdx.x;
    size_t base = ((size_t)b * NN + c * LLEN) * DD + d;
    float A = 1.f, vf = 0.f, vr = 0.f;
    for (int t = 0; t < LLEN; ++t) {
        float lv = bf2f(lam[base + (size_t)t * DD]);
        float uv = bf2f(u[base + (size_t)t * DD]);
        vf = lv * vf + uv;
        vr += uv * A;
        A *= lv;
    }
    size_t o = (size_t)bc * DD + d;
    Aarr[o] = A; Vf[o] = vf; Vr[o] = vr;
}

__global__ __launch_bounds__(256)
void scan_comb(const float* __restrict__ Aarr, const float* __restrict__ Vf,
               const float* __restrict__ Vr, float* __restrict__ cf, float* __restrict__ cr)
{
    int g = blockIdx.x * 256 + threadIdx.x;
    int b = g >> 9, d = g & 511;
    float S = 0.f;
    for (int c = 0; c < CC; ++c) {
        size_t o = (size_t)(b * CC + c) * DD + d;
        cf[o] = S;
        S = Vf[o] + Aarr[o] * S;
    }
    S = 0.f;
    for (int c = CC - 1; c >= 0; --c) {
        size_t o = (size_t)(b * CC + c) * DD + d;
        cr[o] = S;
        S = Vr[o] + Aarr[o] * S;
    }
}

__global__ __launch_bounds__(256)
void scan_final(const unsigned short* __restrict__ lam, const unsigned short* __restrict__ u,
                const float* __restrict__ cf, const float* __restrict__ cr,
                float* __restrict__ h)
{
    int bid = blockIdx.x;            // b*64 + c*2 + dhalf
    int dh = bid & 1, c = (bid >> 1) & 31, b = bid >> 6;
    int d = dh * 256 + threadIdx.x;
    size_t base = ((size_t)b * NN + c * LLEN) * DD + d;
    size_t co   = (size_t)(b * CC + c) * DD + d;

    float hbuf[LLEN];
    float hf = cf[co];
    #pragma unroll
    for (int t = 0; t < LLEN; ++t) {
        float lv = bf2f(lam[base + (size_t)t * DD]);
        float uv = bf2f(u[base + (size_t)t * DD]);
        hf = lv * hf + uv;
        hbuf[t] = hf;
    }
    float hr = cr[co];
    #pragma unroll
    for (int t = LLEN - 1; t >= 0; --t) {
        float lv = bf2f(lam[base + (size_t)t * DD]);
        float uv = bf2f(u[base + (size_t)t * DD]);
        hr = lv * hr + uv;
        h[base + (size_t)t * DD] = hbuf[t] + hr;
    }
}

// hg = h * rsqrt(mean(h^2)+1e-6) * g   (bf16 out; in-place over g safe)
__global__ __launch_bounds__(256)
void rms_mul(const float* __restrict__ h, const unsigned short* __restrict__ g,
             unsigned short* __restrict__ hg)
{
    int row = blockIdx.x;
    size_t base = (size_t)row * DD;
    int tid = threadIdx.x, col = tid * 2;
    float2 v = *(const float2*)&h[base + col];
    float ss = v.x * v.x + v.y * v.y;
    #pragma unroll
    for (int off = 32; off > 0; off >>= 1) ss += __shfl_down(ss, off);
    __shared__ float ps[4];
    __shared__ float scale_s;
    if ((tid & 63) == 0) ps[tid >> 6] = ss;
    __syncthreads();
    if (tid == 0) scale_s = rsqrtf((ps[0] + ps[1] + ps[2] + ps[3]) * (1.f / DD) + 1e-6f);
    __syncthreads();
    float sc = scale_s;
    ushort2 gv = *(const ushort2*)&g[base + col];
    ushort2 o;
    o.x = f2bf(v.x * sc * bf2f(gv.x));
    o.y = f2bf(v.y * sc * bf2f(gv.y));
    *(ushort2*)&hg[base + col] = o;
}

// out = xin + layernorm(y)*gam + bet ; optional bf16 copy of out -> outb
__global__ __launch_bounds__(256)
void add_ln(const float* __restrict__ xin, const unsigned short* __restrict__ y,
            const float* __restrict__ gam, const float* __restrict__ bet,
            float* __restrict__ out, unsigned short* __restrict__ outb)
{
    int row = blockIdx.x;
    size_t base = (size_t)row * DD;
    int tid = threadIdx.x, col = tid * 2;
    ushort2 yv = *(const ushort2*)&y[base + col];
    float vx = bf2f(yv.x), vy = bf2f(yv.y);
    float s = vx + vy;
    float ss = vx * vx + vy * vy;
    #pragma unroll
    for (int off = 32; off > 0; off >>= 1) {
        s  += __shfl_down(s, off);
        ss += __shfl_down(ss, off);
    }
    __shared__ float ps[8];
    __shared__ float stats[2];
    if ((tid & 63) == 0) { ps[tid >> 6] = s; ps[4 + (tid >> 6)] = ss; }
    __syncthreads();
    if (tid == 0) {
        float st  = ps[0] + ps[1] + ps[2] + ps[3];
        float sst = ps[4] + ps[5] + ps[6] + ps[7];
        float mean = st * (1.f / DD);
        float var  = sst * (1.f / DD) - mean * mean;
        stats[0] = mean; stats[1] = rsqrtf(var + 1e-5f);
    }
    __syncthreads();
    float mean = stats[0], inv = stats[1];
    float2 xv = *(const float2*)&xin[base + col];
    float2 gv = *(const float2*)&gam[col];
    float2 bv = *(const float2*)&bet[col];
    float2 o;
    o.x = xv.x + (vx - mean) * inv * gv.x + bv.x;
    o.y = xv.y + (vy - mean) * inv * gv.y + bv.y;
    *(float2*)&out[base + col] = o;
    if (outb) {
        ushort2 ob; ob.x = f2bf(o.x); ob.y = f2bf(o.y);
        *(ushort2*)&outb[base + col] = ob;
    }
}

extern "C" void kernel_launch(void* const* d_in, const int* in_sizes, int n_in,
                              void* d_out, int out_size, void* d_ws, size_t ws_size,
                              hipStream_t stream)
{
    const float* x   = (const float*)d_in[0];
    const int*   lb  = (const int*)d_in[1];
    const float* Wi  = (const float*)d_in[2];
    const float* bi  = (const float*)d_in[3];
    const float* Wf  = (const float*)d_in[4];
    const float* bfp = (const float*)d_in[5];
    const float* Wg  = (const float*)d_in[6];
    const float* bg  = (const float*)d_in[7];
    const float* Wo  = (const float*)d_in[8];
    const float* bo  = (const float*)d_in[9];
    const float* tng = (const float*)d_in[10];
    const float* tnb = (const float*)d_in[11];
    const float* fng = (const float*)d_in[12];
    const float* fnb = (const float*)d_in[13];
    const float* W1  = (const float*)d_in[14];
    const float* b1  = (const float*)d_in[15];
    const float* W2  = (const float*)d_in[16];
    const float* b2  = (const float*)d_in[17];
    const float* W3  = (const float*)d_in[18];
    const float* b3  = (const float*)d_in[19];

    // ---- ws layout: [bf16 transposed weights | 4 bf16 slabs | fp32 aggregates] ----
    unsigned short* wbase = (unsigned short*)d_ws;
    unsigned short* WiT = wbase;                  // 512x512
    unsigned short* WfT = WiT + 262144;
    unsigned short* WgT = WfT + 262144;
    unsigned short* WoT = WgT + 262144;
    unsigned short* W1T = WoT + 262144;           // 1024x512
    unsigned short* W2T = W1T + 524288;
    unsigned short* W3T = W2T + 524288;           // 512x1024
    const size_t WTOT = 4 * 262144 + 3 * 524288;  // 2,621,440 shorts (5 MiB)

    wt_prep<<<dim3(16, 16), 256, 0, stream>>>(Wi, WiT, 512, 512);
    wt_prep<<<dim3(16, 16), 256, 0, stream>>>(Wf, WfT, 512, 512);
    wt_prep<<<dim3(16, 16), 256, 0, stream>>>(Wg, WgT, 512, 512);
    wt_prep<<<dim3(16, 16), 256, 0, stream>>>(Wo, WoT, 512, 512);
    wt_prep<<<dim3(32, 16), 256, 0, stream>>>(W1, W1T, 512, 1024);
    wt_prep<<<dim3(32, 16), 256, 0, stream>>>(W2, W2T, 512, 1024);
    wt_prep<<<dim3(16, 32), 256, 0, stream>>>(W3, W3T, 1024, 512);

    // per batch row: 4 bf16 slabs (NN*DD) + 5 fp32 aggregates (CC*DD)
    const size_t perB = (size_t)4 * NN * DD * 2 + (size_t)5 * CC * DD * 4;
    int Bch = 32;
    while (Bch > 1 && WTOT * 2 + (size_t)Bch * perB > ws_size) Bch >>= 1;
    const int nch = BB / Bch;

    const size_t slabE = (size_t)Bch * NN * DD;   // elements per bf16 slab

    for (int ch = 0; ch < nch; ++ch) {
        const size_t r0 = (size_t)ch * Bch * NN;  // first row of this chunk
        const int Mc = Bch * NN;
        const float* xc = x + r0 * DD;
        unsigned short* S0 = wbase + WTOT;
        unsigned short* S1 = S0 + slabE;
        unsigned short* S2 = S0 + 2 * slabE;
        unsigned short* S3 = S0 + 3 * slabE;
        float* small = (float*)(S0 + 4 * slabE);
        const size_t agg = (size_t)Bch * CC * DD;
        float* Aarr = small;
        float* VfP  = small + agg;
        float* VrP  = small + 2 * agg;
        float* cfP  = small + 3 * agg;
        float* crP  = small + 4 * agg;
        float* hout = (float*)d_out + r0 * DD;    // h -> xr -> final out

        // 0) x -> bf16 (S3)
        cast_bf16<<<Mc / 2, 256, 0, stream>>>(xc, S3);
        // 1) si = silu(x@Wi+bi) -> S0
        gemm128<1><<<dim3(DD / 128, Mc / 128), 256, 0, stream>>>(
            S3, WiT, bi, nullptr, S0, nullptr, nullptr, DD, DD);
        // 2) f-GEMM: lam -> S1, u = (1-lam)*si -> S0 (in-place over si)
        gemm128<3><<<dim3(DD / 128, Mc / 128), 256, 0, stream>>>(
            S3, WfT, bfp, S0, S1, S0, lb, DD, DD);
        // 3) g = sigm(x@Wg+bg) -> S2
        gemm128<2><<<dim3(DD / 128, Mc / 128), 256, 0, stream>>>(
            S3, WgT, bg, nullptr, S2, nullptr, nullptr, DD, DD);
        // 4-6) bidirectional chunked scan: lam(S1), u(S0) -> h (fp32, d_out region)
        scan_agg<<<Bch * CC, 512, 0, stream>>>(S1, S0, Aarr, VfP, VrP);
        scan_comb<<<(Bch * DD) / 256, 256, 0, stream>>>(Aarr, VfP, VrP, cfP, crP);
        scan_final<<<Bch * CC * 2, 256, 0, stream>>>(S1, S0, cfP, crP, hout);
        // 7) hg = rms_norm(h)*g -> S2 (in place)
        rms_mul<<<Mc, 256, 0, stream>>>(hout, S2, S2);
        // 8) y2 = hg@Wo + bo -> S0
        gemm128<0><<<dim3(DD / 128, Mc / 128), 256, 0, stream>>>(
            S2, WoT, bo, nullptr, S0, nullptr, nullptr, DD, DD);
        // 9) xr = x + LN(y2)*tn_g+tn_b -> hout (fp32) + S3 (bf16)
        add_ln<<<Mc, 256, 0, stream>>>(xc, S0, tng, tnb, hout, S3);
        // 10) s = silu(xr@W1+b1) -> S1
        gemm128<1><<<dim3(DGG / 128, Mc / 128), 256, 0, stream>>>(
            S3, W1T, b1, nullptr, S1, nullptr, nullptr, DD, DGG);
        // 11) v = s * (xr@W2+b2) -> S1 (in place)
        gemm128<4><<<dim3(DGG / 128, Mc / 128), 256, 0, stream>>>(
            S3, W2T, b2, S1, S1, nullptr, nullptr, DD, DGG);
        // 12) y4 = v@W3 + b3 -> S0
        gemm128<0><<<dim3(DD / 128, Mc / 128), 256, 0, stream>>>(
            S1, W3T, b3, nullptr, S0, nullptr, nullptr, DGG, DD);
        // 13) out = xr + LN(y4)*fn_g+fn_b (fp32, in place in d_out region)
        add_ln<<<Mc, 256, 0, stream>>>(hout, S0, fng, fnb, hout, nullptr);
    }
}